// Round 1
// baseline (13228.888 us; speedup 1.0000x reference)
//
#include <hip/hip_runtime.h>
#include <hip/hip_bf16.h>
#include <stdint.h>
#include <stddef.h>

// Problem dims
#define SEQ   2048
#define BATCH 32
#define HID   512
#define G4    2048   // 4*HID
#define NSL   64     // workgroups (slices) per direction
#define UPS   8      // hidden units per slice (NSL*UPS == HID)

typedef __bf16 bf16;
typedef bf16  bf16x8 __attribute__((ext_vector_type(8)));
typedef float f32x4  __attribute__((ext_vector_type(4)));

// ---------------------------------------------------------------------------
// Prep 1: embedding gather -> bf16 [S*B][H]; also h0 -> hbuf slot 0 (both dirs)
// ---------------------------------------------------------------------------
__global__ void k_embed(const int* __restrict__ tokens,
                        const float* __restrict__ h0,
                        const float* __restrict__ table,
                        bf16* __restrict__ embT,
                        bf16* __restrict__ hbuf_f,
                        bf16* __restrict__ hbuf_b)
{
    int wid  = (blockIdx.x * blockDim.x + threadIdx.x) >> 6;
    int lane = threadIdx.x & 63;
    int k = lane * 8;                      // 64 lanes * 8 = 512 = HID
    if (wid < SEQ * BATCH) {
        int tok = tokens[wid];
        const float* src = table + (size_t)tok * HID;
        float4 a = *(const float4*)(src + k);
        float4 b = *(const float4*)(src + k + 4);
        bf16x8 v;
        v[0]=(bf16)a.x; v[1]=(bf16)a.y; v[2]=(bf16)a.z; v[3]=(bf16)a.w;
        v[4]=(bf16)b.x; v[5]=(bf16)b.y; v[6]=(bf16)b.z; v[7]=(bf16)b.w;
        *(bf16x8*)(embT + (size_t)wid * HID + k) = v;
    } else if (wid < SEQ * BATCH + BATCH) {
        int b = wid - SEQ * BATCH;
        const float* src = h0 + (size_t)b * HID;
        bf16x8 v;
        #pragma unroll
        for (int j = 0; j < 8; j++) v[j] = (bf16)src[k + j];
        *(bf16x8*)(hbuf_f + (size_t)b * HID + k) = v;   // slot 0
        *(bf16x8*)(hbuf_b + (size_t)b * HID + k) = v;
    }
}

// ---------------------------------------------------------------------------
// Prep 2: transpose+convert weights: [HID][G4] fp32 -> [G4][HID] bf16
// blockIdx.y selects matrix {wx_f, wx_b, wh_f, wh_b}; dst stride = G4*HID
// ---------------------------------------------------------------------------
__global__ void k_transpose(const float* s0, const float* s1,
                            const float* s2, const float* s3,
                            bf16* __restrict__ dst)
{
    const float* srcs[4] = {s0, s1, s2, s3};
    const float* src = srcs[blockIdx.y];
    bf16* d = dst + (size_t)blockIdx.y * ((size_t)G4 * HID);
    int c = blockIdx.x * 256 + threadIdx.x;          // 8 blocks * 256 = 2048
    for (int k = 0; k < HID; k++)                    // coalesced reads over c
        d[(size_t)c * HID + k] = (bf16)src[(size_t)k * G4 + c];
}

// ---------------------------------------------------------------------------
// Persistent bidirectional LSTM recurrence.
// 128 wgs: dir = bid&1, slice = bid>>1 owns units [slice*8, slice*8+8).
// LDS: [0,32K)  whT slice, swizzled rows [32][512] bf16
//      [32K,64K) h_t staged, swizzled rows [32][512] bf16 (gbuf aliases base)
// ---------------------------------------------------------------------------
__global__ __launch_bounds__(256, 1) void k_lstm(
    const bf16* __restrict__ embT,
    const bf16* __restrict__ wxT,    // [2][G4][HID] bf16
    const bf16* __restrict__ whT,    // [2][G4][HID] bf16
    const float* __restrict__ bx_f, const float* __restrict__ bh_f,
    const float* __restrict__ bx_b, const float* __restrict__ bh_b,
    const float* __restrict__ h0,
    bf16* __restrict__ hbuf_f, bf16* __restrict__ hbuf_b,
    uint32_t* __restrict__ flags_f, uint32_t* __restrict__ flags_b,
    float* __restrict__ out)
{
    __shared__ __align__(16) char smem[65536];
    float* gbuf = (float*)(smem + 32768);   // [32][36] fp32, aliases h region

    const int tid   = threadIdx.x;
    const int bid   = blockIdx.x;
    const int dir   = bid & 1;
    const int slice = bid >> 1;
    const int u0    = slice * UPS;

    const bf16* wxTs = wxT + (size_t)dir * ((size_t)G4 * HID);
    const bf16* whTs = whT + (size_t)dir * ((size_t)G4 * HID);
    const float* bx  = dir ? bx_b : bx_f;
    const float* bh  = dir ? bh_b : bh_f;
    bf16* hbuf       = dir ? hbuf_b : hbuf_f;
    uint32_t* flags  = dir ? flags_b : flags_f;

    // ---- load whT slice into LDS (swizzled: addr = row*1024 + (kb ^ ((row&7)<<4)))
    // local col lc in [0,32): gate = lc>>3, unit = lc&7 -> global col gate*512+u0+unit
    #pragma unroll
    for (int i = 0; i < 8; i++) {
        int e  = i * 2048 + tid * 8;       // elem in [0,16384)
        int lc = e >> 9;
        int k  = e & 511;                  // multiple of 8
        int c  = (lc >> 3) * HID + u0 + (lc & 7);
        bf16x8 v = *(const bf16x8*)(whTs + (size_t)c * HID + k);
        *(bf16x8*)(smem + lc * 1024 + ((k * 2) ^ ((lc & 7) << 4))) = v;
    }

    // wave/tile assignment: 4 waves = 2 M-tiles x 2 N-tiles of 16x16
    const int w     = tid >> 6;
    const int lane  = tid & 63;
    const int mtile = w >> 1;              // batch tile 0..1
    const int ntile = w & 1;               // col tile 0..1
    const int lrow  = lane & 15;
    const int lc_b  = ntile * 16 + lrow;                       // local col 0..31
    const int gcol  = (lc_b >> 3) * HID + u0 + (lc_b & 7);     // global gate col
    const float bias = bx[gcol] + bh[gcol];

    const int arow   = mtile * 16 + lrow;       // A rows (batch) 0..31
    const int brow_off = lc_b * 1024;
    const int bswz     = (lc_b & 7) << 4;
    const int arow_off = 32768 + arow * 1024;
    const int aswz     = (arow & 7) << 4;

    // pointwise: 1 element per thread
    const int pb = tid >> 3;               // batch 0..31
    const int pu = tid & 7;                // unit  0..7
    float creg = h0[(size_t)pb * HID + u0 + pu];

    __syncthreads();

    for (int t = 0; t < SEQ; t++) {
        const int s = dir ? (SEQ - 1 - t) : t;

        // ---- phase X: acc = bias + emb[s] @ wx_slice (all cached loads) ----
        f32x4 acc = {bias, bias, bias, bias};
        const bf16* aX = embT + ((size_t)s * BATCH + arow) * HID + ((lane >> 4) * 8);
        const bf16* bX = wxTs + (size_t)gcol * HID + ((lane >> 4) * 8);
        #pragma unroll
        for (int kk = 0; kk < 16; kk++) {
            bf16x8 a = *(const bf16x8*)(aX + kk * 32);
            bf16x8 b = *(const bf16x8*)(bX + kk * 32);
            acc = __builtin_amdgcn_mfma_f32_16x16x32_bf16(a, b, acc, 0, 0, 0);
        }

        // ---- wait for h_t (slot t); slot 0 comes from prep kernel ----
        if (t > 0 && tid == 0) {
            uint64_t t0c = __builtin_amdgcn_s_memrealtime();
            while (__hip_atomic_load(&flags[t], __ATOMIC_RELAXED,
                                     __HIP_MEMORY_SCOPE_AGENT) != (uint32_t)NSL) {
                __builtin_amdgcn_s_sleep(1);
                if (__builtin_amdgcn_s_memrealtime() - t0c > 10000000ULL) break; // ~0.1s
            }
        }
        __syncthreads();

        // ---- stage h_t into LDS via agent-scope (LLC) loads ----
        {
            const char* hsrc = (const char*)(hbuf + (size_t)t * (BATCH * HID));
            unsigned long long hv[16];
            #pragma unroll
            for (int j = 0; j < 16; j++)
                hv[j] = __hip_atomic_load(
                    (const unsigned long long*)(hsrc + (size_t)j * 2048 + tid * 8),
                    __ATOMIC_RELAXED, __HIP_MEMORY_SCOPE_AGENT);
            #pragma unroll
            for (int j = 0; j < 16; j++) {
                int e  = j * 1024 + tid * 4;   // bf16 elem index
                int m  = e >> 9;
                int kb = (e & 511) << 1;       // byte offset, multiple of 8
                *(unsigned long long*)(smem + 32768 + m * 1024 +
                                       (kb ^ ((m & 7) << 4))) = hv[j];
            }
        }
        __syncthreads();

        // ---- phase H: acc += h_t @ wh_slice (LDS) ----
        #pragma unroll
        for (int kk = 0; kk < 16; kk++) {
            int kb = kk * 64 + ((lane >> 4) << 4);
            bf16x8 a = *(const bf16x8*)(smem + arow_off + (kb ^ aswz));
            bf16x8 b = *(const bf16x8*)(smem + brow_off + (kb ^ bswz));
            acc = __builtin_amdgcn_mfma_f32_16x16x32_bf16(a, b, acc, 0, 0, 0);
        }
        __syncthreads();   // h reads done; gbuf may now overwrite the region

        // ---- gates -> gbuf (C/D layout: col = lane&15, row = (lane>>4)*4+r) ----
        {
            int r0 = mtile * 16 + (lane >> 4) * 4;
            #pragma unroll
            for (int r = 0; r < 4; r++)
                gbuf[(r0 + r) * 36 + lc_b] = acc[r];
        }
        __syncthreads();

        // ---- pointwise LSTM cell ----
        {
            float gi = gbuf[pb * 36 + pu];
            float gf = gbuf[pb * 36 + 8 + pu];
            float gg = gbuf[pb * 36 + 16 + pu];
            float go = gbuf[pb * 36 + 24 + pu];
            float si = 1.f / (1.f + __expf(-gi));
            float sf = 1.f / (1.f + __expf(-gf));
            float so = 1.f / (1.f + __expf(-go));
            float e2 = __expf(2.f * gg);
            float tg = (e2 - 1.f) / (e2 + 1.f);
            creg = sf * creg + si * tg;
            float ec = __expf(2.f * creg);
            float tc = (ec - 1.f) / (ec + 1.f);
            float hv = so * tc;
            hbuf[((size_t)(t + 1) * BATCH + pb) * HID + u0 + pu] = (bf16)hv;
            out[(size_t)pb * ((size_t)SEQ * 2 * HID) + (size_t)s * (2 * HID)
                + dir * HID + u0 + pu] = hv;
        }
        __syncthreads();
        // release: waitcnt + buffer_wbl2 sc1 + atomic -> h slice visible at LLC
        if (tid == 0)
            __hip_atomic_fetch_add(&flags[t + 1], 1u, __ATOMIC_RELEASE,
                                   __HIP_MEMORY_SCOPE_AGENT);
    }
}

// ---------------------------------------------------------------------------
// Workspace layout (bytes):
//   embT   :         0 ..  67,108,864   bf16 [S*B][H]
//   hbuf_f :  67,108,864 .. 134,250,496  bf16 [S+1][B][H]
//   hbuf_b : 134,250,496 .. 201,392,128
//   wxT    : 201,392,128 .. 205,586,432  bf16 [2][G4][H]
//   whT    : 205,586,432 .. 209,780,736  bf16 [2][G4][H]
//   flags  : 209,780,736 .. 209,813,504  2 x 4096 uint32 (zeroed per launch)
// ---------------------------------------------------------------------------
extern "C" void kernel_launch(void* const* d_in, const int* in_sizes, int n_in,
                              void* d_out, int out_size, void* d_ws, size_t ws_size,
                              hipStream_t stream)
{
    const int*   tokens = (const int*)  d_in[0];
    const float* h0     = (const float*)d_in[1];
    const float* table  = (const float*)d_in[2];
    const float* wx_f   = (const float*)d_in[3];
    const float* bx_f   = (const float*)d_in[4];
    const float* wh_f   = (const float*)d_in[5];
    const float* bh_f   = (const float*)d_in[6];
    const float* wx_b   = (const float*)d_in[7];
    const float* bx_b   = (const float*)d_in[8];
    const float* wh_b   = (const float*)d_in[9];
    const float* bh_b   = (const float*)d_in[10];
    float* out = (float*)d_out;
    char*  ws  = (char*)d_ws;

    const size_t OFF_EMBT  = 0;
    const size_t OFF_HF    = 67108864ULL;
    const size_t OFF_HB    = OFF_HF  + 67141632ULL;
    const size_t OFF_WXT   = OFF_HB  + 67141632ULL;
    const size_t OFF_WHT   = OFF_WXT + 4194304ULL;
    const size_t OFF_FLAGS = OFF_WHT + 4194304ULL;

    bf16* embT   = (bf16*)(ws + OFF_EMBT);
    bf16* hbuf_f = (bf16*)(ws + OFF_HF);
    bf16* hbuf_b = (bf16*)(ws + OFF_HB);
    bf16* wxT    = (bf16*)(ws + OFF_WXT);
    bf16* whT    = (bf16*)(ws + OFF_WHT);
    uint32_t* flags_f = (uint32_t*)(ws + OFF_FLAGS);
    uint32_t* flags_b = (uint32_t*)(ws + OFF_FLAGS + 16384);

    // flags must start at 0 every launch (ws is poisoned 0xAA)
    hipMemsetAsync(ws + OFF_FLAGS, 0, 32768, stream);

    // embedding gather + h0 slot-0
    {
        int waves  = SEQ * BATCH + BATCH;
        int blocks = (waves * 64 + 255) / 256;
        k_embed<<<blocks, 256, 0, stream>>>(tokens, h0, table, embT, hbuf_f, hbuf_b);
    }
    // weight transposes: slots {wxT_f, wxT_b, whT_f, whT_b} contiguous
    k_transpose<<<dim3(8, 4), 256, 0, stream>>>(wx_f, wx_b, wh_f, wh_b, wxT);

    // persistent recurrence: 128 wgs (64 per direction), all co-resident
    k_lstm<<<128, 256, 0, stream>>>(embT, wxT, whT,
                                    bx_f, bh_f, bx_b, bh_b, h0,
                                    hbuf_f, hbuf_b, flags_f, flags_b, out);
}

// Round 2
// 11623.066 us; speedup vs baseline: 1.1382x; 1.1382x over previous
//
#include <hip/hip_runtime.h>
#include <hip/hip_bf16.h>
#include <stdint.h>
#include <stddef.h>

// Problem dims
#define SEQ   2048
#define BATCH 32
#define HID   512
#define G4    2048   // 4*HID
#define NSL   64     // workgroups (slices) per direction
#define UPS   8      // hidden units per slice (NSL*UPS == HID)

typedef __bf16 bf16;
typedef bf16  bf16x8 __attribute__((ext_vector_type(8)));
typedef float f32x4  __attribute__((ext_vector_type(4)));

// ---------------------------------------------------------------------------
// Prep 1: embedding gather -> bf16 [S*B][H]; h0 -> hbuf slot 0 (slice-major)
// hbuf layout: [t][slice][b][u] bf16, slot stride = BATCH*HID = 16384 elems
// ---------------------------------------------------------------------------
__global__ void k_embed(const int* __restrict__ tokens,
                        const float* __restrict__ h0,
                        const float* __restrict__ table,
                        bf16* __restrict__ embT,
                        bf16* __restrict__ hbuf_f,
                        bf16* __restrict__ hbuf_b)
{
    int wid  = (blockIdx.x * blockDim.x + threadIdx.x) >> 6;
    int lane = threadIdx.x & 63;
    int k = lane * 8;                      // 64 lanes * 8 = 512 = HID
    if (wid < SEQ * BATCH) {
        int tok = tokens[wid];
        const float* src = table + (size_t)tok * HID;
        float4 a = *(const float4*)(src + k);
        float4 b = *(const float4*)(src + k + 4);
        bf16x8 v;
        v[0]=(bf16)a.x; v[1]=(bf16)a.y; v[2]=(bf16)a.z; v[3]=(bf16)a.w;
        v[4]=(bf16)b.x; v[5]=(bf16)b.y; v[6]=(bf16)b.z; v[7]=(bf16)b.w;
        *(bf16x8*)(embT + (size_t)wid * HID + k) = v;
    } else if (wid < SEQ * BATCH + BATCH) {
        int b = wid - SEQ * BATCH;
        const float* src = h0 + (size_t)b * HID;
        bf16x8 v;
        #pragma unroll
        for (int j = 0; j < 8; j++) v[j] = (bf16)src[k + j];
        // slot 0, slice = lane, units 0..7: offset = lane*256 + b*8
        *(bf16x8*)(hbuf_f + lane * (BATCH * UPS) + b * UPS) = v;
        *(bf16x8*)(hbuf_b + lane * (BATCH * UPS) + b * UPS) = v;
    }
}

// ---------------------------------------------------------------------------
// Prep 2: transpose+convert weights: [HID][G4] fp32 -> [G4][HID] bf16
// ---------------------------------------------------------------------------
__global__ void k_transpose(const float* s0, const float* s1,
                            const float* s2, const float* s3,
                            bf16* __restrict__ dst)
{
    const float* srcs[4] = {s0, s1, s2, s3};
    const float* src = srcs[blockIdx.y];
    bf16* d = dst + (size_t)blockIdx.y * ((size_t)G4 * HID);
    int c = blockIdx.x * 256 + threadIdx.x;          // 8 blocks * 256 = 2048
    for (int k = 0; k < HID; k++)                    // coalesced reads over c
        d[(size_t)c * HID + k] = (bf16)src[(size_t)k * G4 + c];
}

// ---------------------------------------------------------------------------
// Persistent bidirectional LSTM recurrence.
// 128 wgs: dir = bid&1, slice = bid>>1 owns units [slice*8, slice*8+8).
// LDS: [0,32K)  whT slice, swizzled rows [32 cols][512 k] bf16
//      [32K,64K) h_t staged, swizzled rows [32 b][512 k] bf16 (gbuf aliases)
// Sync: per-slice monotonic flag word (value = steps produced), sc1 h stores,
// manual vmcnt(0) release — NO cache-maintenance ops in the loop.
// ---------------------------------------------------------------------------
__global__ __launch_bounds__(256, 1) void k_lstm(
    const bf16* __restrict__ embT,
    const bf16* __restrict__ wxT,    // [2][G4][HID] bf16
    const bf16* __restrict__ whT,    // [2][G4][HID] bf16
    const float* __restrict__ bx_f, const float* __restrict__ bh_f,
    const float* __restrict__ bx_b, const float* __restrict__ bh_b,
    const float* __restrict__ h0,
    bf16* __restrict__ hbuf_f, bf16* __restrict__ hbuf_b,
    uint32_t* __restrict__ flags_f, uint32_t* __restrict__ flags_b,
    float* __restrict__ out)
{
    __shared__ __align__(16) char smem[65536];
    float* gbuf = (float*)(smem + 32768);   // [32][36] fp32, aliases h region

    const int tid   = threadIdx.x;
    const int bid   = blockIdx.x;
    const int dir   = bid & 1;
    const int slice = bid >> 1;
    const int u0    = slice * UPS;

    const bf16* wxTs = wxT + (size_t)dir * ((size_t)G4 * HID);
    const bf16* whTs = whT + (size_t)dir * ((size_t)G4 * HID);
    const float* bx  = dir ? bx_b : bx_f;
    const float* bh  = dir ? bh_b : bh_f;
    bf16* hbuf       = dir ? hbuf_b : hbuf_f;
    uint32_t* flags  = dir ? flags_b : flags_f;

    // ---- load whT slice into LDS (swizzled: addr = row*1024 + (kb ^ ((row&7)<<4)))
    #pragma unroll
    for (int i = 0; i < 8; i++) {
        int e  = i * 2048 + tid * 8;       // elem in [0,16384)
        int lc = e >> 9;
        int k  = e & 511;                  // multiple of 8
        int c  = (lc >> 3) * HID + u0 + (lc & 7);
        bf16x8 v = *(const bf16x8*)(whTs + (size_t)c * HID + k);
        *(bf16x8*)(smem + lc * 1024 + ((k * 2) ^ ((lc & 7) << 4))) = v;
    }

    // wave/tile assignment: 4 waves = 2 M-tiles x 2 N-tiles of 16x16
    const int w     = tid >> 6;
    const int lane  = tid & 63;
    const int mtile = w >> 1;              // batch tile 0..1
    const int ntile = w & 1;               // col tile 0..1
    const int lrow  = lane & 15;
    const int lc_b  = ntile * 16 + lrow;                       // local col 0..31
    const int gcol  = (lc_b >> 3) * HID + u0 + (lc_b & 7);     // global gate col
    const float bias = bx[gcol] + bh[gcol];

    const int arow   = mtile * 16 + lrow;       // A rows (batch) 0..31
    const int brow_off = lc_b * 1024;
    const int bswz     = (lc_b & 7) << 4;
    const int arow_off = 32768 + arow * 1024;
    const int aswz     = (arow & 7) << 4;

    // staging decode (per thread): slice_s = j*4 + w, b = (lane)>>1, u = (lane&1)*4
    const int sb    = lane >> 1;                 // staging LDS row (batch)
    const int scol0 = w * 16 + (lane & 1) * 8;   // column byte base (j adds j*64)
    const int sswz  = (sb & 7) << 4;

    // pointwise: wave 0 only, 4 units per thread
    const int pb = lane >> 1;              // batch 0..31
    const int pu = (lane & 1) * 4;         // unit group {0,4}
    f32x4 creg = {0.f, 0.f, 0.f, 0.f};
    if (tid < 64)
        creg = *(const f32x4*)(h0 + (size_t)pb * HID + u0 + pu);

    __syncthreads();

    for (int t = 0; t < SEQ; t++) {
        const int s = dir ? (SEQ - 1 - t) : t;

        // ---- phase X: acc = bias + emb[s] @ wx_slice (cached loads) ----
        f32x4 acc = {bias, bias, bias, bias};
        const bf16* aX = embT + ((size_t)s * BATCH + arow) * HID + ((lane >> 4) * 8);
        const bf16* bX = wxTs + (size_t)gcol * HID + ((lane >> 4) * 8);
        #pragma unroll
        for (int kk = 0; kk < 16; kk++) {
            bf16x8 a = *(const bf16x8*)(aX + kk * 32);
            bf16x8 b = *(const bf16x8*)(bX + kk * 32);
            acc = __builtin_amdgcn_mfma_f32_16x16x32_bf16(a, b, acc, 0, 0, 0);
        }

        // ---- self-poll: every wave's 64 lanes poll the 64 slice flags ----
        if (t > 0) {
            const uint32_t* fp = flags + lane;
            uint64_t t0c = __builtin_amdgcn_s_memrealtime();
            for (;;) {
                uint32_t v = __hip_atomic_load(fp, __ATOMIC_RELAXED,
                                               __HIP_MEMORY_SCOPE_AGENT);
                if (__all(v >= (uint32_t)t)) break;
                __builtin_amdgcn_s_sleep(1);
                if (__builtin_amdgcn_s_memrealtime() - t0c > 2000000ULL) break; // ~20ms
            }
        }
        __atomic_signal_fence(__ATOMIC_ACQUIRE);

        // ---- stage h_t into LDS via agent-scope (LLC) loads ----
        {
            const char* hsrc = (const char*)hbuf + (size_t)t * (BATCH * HID) * 2;
            unsigned long long hv[16];
            #pragma unroll
            for (int j = 0; j < 16; j++)
                hv[j] = __hip_atomic_load(
                    (const unsigned long long*)(hsrc + (size_t)(j * 256 + tid) * 8),
                    __ATOMIC_RELAXED, __HIP_MEMORY_SCOPE_AGENT);
            #pragma unroll
            for (int j = 0; j < 16; j++)
                *(unsigned long long*)(smem + 32768 + sb * 1024 +
                                       ((j * 64 + scol0) ^ sswz)) = hv[j];
        }
        __syncthreads();

        // ---- phase H: acc += h_t @ wh_slice (LDS) ----
        #pragma unroll
        for (int kk = 0; kk < 16; kk++) {
            int kb = kk * 64 + ((lane >> 4) << 4);
            bf16x8 a = *(const bf16x8*)(smem + arow_off + (kb ^ aswz));
            bf16x8 b = *(const bf16x8*)(smem + brow_off + (kb ^ bswz));
            acc = __builtin_amdgcn_mfma_f32_16x16x32_bf16(a, b, acc, 0, 0, 0);
        }
        __syncthreads();   // h reads done; gbuf may now overwrite the region

        // ---- gates -> gbuf (C/D layout: col = lane&15, row = (lane>>4)*4+r) ----
        {
            int r0 = mtile * 16 + (lane >> 4) * 4;
            #pragma unroll
            for (int r = 0; r < 4; r++)
                gbuf[(r0 + r) * 36 + lc_b] = acc[r];
        }
        __syncthreads();

        // ---- pointwise LSTM cell: wave 0, 4 units/thread ----
        if (tid < 64) {
            f32x4 gi = *(const f32x4*)(gbuf + pb * 36 + pu);
            f32x4 gf = *(const f32x4*)(gbuf + pb * 36 + 8 + pu);
            f32x4 gg = *(const f32x4*)(gbuf + pb * 36 + 16 + pu);
            f32x4 go = *(const f32x4*)(gbuf + pb * 36 + 24 + pu);
            float hv[4];
            #pragma unroll
            for (int j = 0; j < 4; j++) {
                float si = 1.f / (1.f + __expf(-gi[j]));
                float sf = 1.f / (1.f + __expf(-gf[j]));
                float so = 1.f / (1.f + __expf(-go[j]));
                float e2 = __expf(2.f * gg[j]);
                float tg = (e2 - 1.f) / (e2 + 1.f);
                creg[j] = sf * creg[j] + si * tg;
                float ec = __expf(2.f * creg[j]);
                float tc = (ec - 1.f) / (ec + 1.f);
                hv[j] = so * tc;
            }
            // pack 4 bf16 -> one 8B sc1 (LLC write-through) store, slice-major
            union { bf16 h[4]; unsigned long long q; } pk;
            #pragma unroll
            for (int j = 0; j < 4; j++) pk.h[j] = (bf16)hv[j];
            __hip_atomic_store(
                (unsigned long long*)(hbuf + (size_t)(t + 1) * (BATCH * HID)
                                      + slice * (BATCH * UPS) + pb * UPS + pu),
                pk.q, __ATOMIC_RELAXED, __HIP_MEMORY_SCOPE_AGENT);
            __atomic_signal_fence(__ATOMIC_SEQ_CST);
            __builtin_amdgcn_s_waitcnt(0x0F70);   // vmcnt(0): h stores at LLC
            if (tid == 0)
                __hip_atomic_store(&flags[slice], (uint32_t)(t + 1),
                                   __ATOMIC_RELAXED, __HIP_MEMORY_SCOPE_AGENT);
            // out store AFTER flag — off the inter-wg critical path
            float4 ov = {hv[0], hv[1], hv[2], hv[3]};
            *(float4*)(out + (size_t)pb * ((size_t)SEQ * 2 * HID)
                       + (size_t)s * (2 * HID) + dir * HID + u0 + pu) = ov;
        }
        __syncthreads();   // gbuf reads done before next staging overwrites
    }
}

// ---------------------------------------------------------------------------
// Workspace layout (bytes):
//   embT   :         0 ..  67,108,864   bf16 [S*B][H]
//   hbuf_f :  67,108,864 .. 134,250,496  bf16 [S+1][64][32][8]
//   hbuf_b : 134,250,496 .. 201,392,128
//   wxT    : 201,392,128 .. 205,586,432  bf16 [2][G4][H]
//   whT    : 205,586,432 .. 209,780,736  bf16 [2][G4][H]
//   flags  : 209,780,736 .. +512         2 x 64 uint32 (zeroed per launch)
// ---------------------------------------------------------------------------
extern "C" void kernel_launch(void* const* d_in, const int* in_sizes, int n_in,
                              void* d_out, int out_size, void* d_ws, size_t ws_size,
                              hipStream_t stream)
{
    const int*   tokens = (const int*)  d_in[0];
    const float* h0     = (const float*)d_in[1];
    const float* table  = (const float*)d_in[2];
    const float* wx_f   = (const float*)d_in[3];
    const float* bx_f   = (const float*)d_in[4];
    const float* wh_f   = (const float*)d_in[5];
    const float* bh_f   = (const float*)d_in[6];
    const float* wx_b   = (const float*)d_in[7];
    const float* bx_b   = (const float*)d_in[8];
    const float* wh_b   = (const float*)d_in[9];
    const float* bh_b   = (const float*)d_in[10];
    float* out = (float*)d_out;
    char*  ws  = (char*)d_ws;

    const size_t OFF_EMBT  = 0;
    const size_t OFF_HF    = 67108864ULL;
    const size_t OFF_HB    = OFF_HF  + 67141632ULL;
    const size_t OFF_WXT   = OFF_HB  + 67141632ULL;
    const size_t OFF_WHT   = OFF_WXT + 4194304ULL;
    const size_t OFF_FLAGS = OFF_WHT + 4194304ULL;

    bf16* embT   = (bf16*)(ws + OFF_EMBT);
    bf16* hbuf_f = (bf16*)(ws + OFF_HF);
    bf16* hbuf_b = (bf16*)(ws + OFF_HB);
    bf16* wxT    = (bf16*)(ws + OFF_WXT);
    bf16* whT    = (bf16*)(ws + OFF_WHT);
    uint32_t* flags_f = (uint32_t*)(ws + OFF_FLAGS);
    uint32_t* flags_b = (uint32_t*)(ws + OFF_FLAGS + 256);

    // flags must start at 0 every launch (ws is poisoned 0xAA)
    hipMemsetAsync(ws + OFF_FLAGS, 0, 512, stream);

    // embedding gather + h0 slot-0
    {
        int waves  = SEQ * BATCH + BATCH;
        int blocks = (waves * 64 + 255) / 256;
        k_embed<<<blocks, 256, 0, stream>>>(tokens, h0, table, embT, hbuf_f, hbuf_b);
    }
    // weight transposes: slots {wxT_f, wxT_b, whT_f, whT_b} contiguous
    k_transpose<<<dim3(8, 4), 256, 0, stream>>>(wx_f, wx_b, wh_f, wh_b, wxT);

    // persistent recurrence: 128 wgs (64 per direction), all co-resident
    k_lstm<<<128, 256, 0, stream>>>(embT, wxT, whT,
                                    bx_f, bh_f, bx_b, bh_b, h0,
                                    hbuf_f, hbuf_b, flags_f, flags_b, out);
}